// Round 3
// baseline (80208.569 us; speedup 1.0000x reference)
//
#include <hip/hip_runtime.h>
#include <hip/hip_cooperative_groups.h>
#include <math.h>

// RNNAttentionDecoder on MI355X — round 3: single persistent cooperative kernel.
// 256 blocks x 512 threads (1 block/CU, 2 waves/SIMD), 4 grid.sync()/step instead
// of 4 kernel dispatches (kills dispatch+drain overhead, the round-2 residual).
// All f32 (argmax feedback forbids bf16; no fp32 MFMA on CDNA4).
// LDS transposes use XOR swizzle (k4 ^ b) -> conflict-free ds_read_b128.

namespace cg = cooperative_groups;
typedef unsigned long long u64;

#define NB 32
#define NS 196
#define ND 512
#define NK 256
#define NV 10000
#define NT 300
#define NBLK 256
#define NTHR 512

__device__ __forceinline__ float sigm(float x) { return 1.0f / (1.0f + expf(-x)); }

// monotone f32 -> u32, packed with (0xFFFFFFFF - v): max() = (max value, smallest idx)
__device__ __forceinline__ u64 packmax(float x, int v) {
  unsigned u = __float_as_uint(x);
  u = (u & 0x80000000u) ? ~u : (u | 0x80000000u);
  return ((u64)u << 32) | (u64)(0xFFFFFFFFu - (unsigned)v);
}

// swizzled float4-slot index for element row b, float4-col k4; W4 % 32 == 0.
// bank-granule = (k4 ^ b) & 31 -> distinct across b lanes, conflict-free.
__device__ __forceinline__ int swz4(int b, int k4, int W4) {
  return b * W4 + ((k4 & ~31) | ((k4 ^ b) & 31));
}

struct Params {
  const float *x, *emb, *Wk, *bk, *Wv, *bv, *Wq, *bq, *Wp, *bp;
  const float *Wih0, *Whh0, *bih0, *bhh0, *Wih1, *Whh1, *bih1, *bhh1;
  float *out, *keys, *values, *h0t, *h1t, *c0, *c1, *ctx;
  u64 *amax;
};

__global__ __launch_bounds__(NTHR, 2) void k_all(Params p) {
  cg::grid_group grid = cg::this_grid();
  extern __shared__ float lds[];          // swizzled inT; max [32][1024] = 128 KiB
  __shared__ int tok_lds[32];
  __shared__ float gp[2][4][2][32];       // [kh][gate][dl][b] partial gate sums
  __shared__ float attq[256];
  __shared__ float attb[512];
  __shared__ float red[256];
  __shared__ float smx[256];
  __shared__ u64 cand[8][32];

  const int bid = blockIdx.x;
  const int t = threadIdx.x;
  const int lane = t & 63;
  const int w = t >> 6;

  // ================= init: zero state, seed argmax (tok=0) =================
  {
    const int g = bid * NTHR + t;
    if (g < 16384) { p.h0t[g] = 0.0f; p.h1t[g] = 0.0f; }
    else if (g < 32768) { p.c0[g - 16384] = 0.0f; p.c1[g - 16384] = 0.0f; }
    else if (g < 40960) { p.ctx[g - 32768] = 0.0f; }
    if (g < 256) p.amax[g] = (g < 32) ? ((1ull << 32) | 0xFFFFFFFFull) : 0ull;
  }

  // ================= keys/values (once): block = (kc, b) =================
  {
    const int kc = bid & 7, bb = bid >> 3;
    const int kl = t & 31, sg = t >> 5;        // sg 0..15
    const int k = kc * 32 + kl;
    float ak[13], av[13];
#pragma unroll
    for (int i = 0; i < 13; ++i) { ak[i] = 0.f; av[i] = 0.f; }
    const float* wkr = p.Wk + (size_t)k * ND;
    const float* wvr = p.Wv + (size_t)k * ND;
    const float* xb = p.x + (size_t)bb * NS * ND;
    for (int j = 0; j < ND; j += 4) {
      const float4 wk4 = *(const float4*)(wkr + j);
      const float4 wv4 = *(const float4*)(wvr + j);
#pragma unroll
      for (int si = 0; si < 13; ++si) {
        const int s = sg + si * 16;
        if (s < NS) {
          const float4 xv = *(const float4*)(xb + (size_t)s * ND + j);
          ak[si] += wk4.x * xv.x + wk4.y * xv.y + wk4.z * xv.z + wk4.w * xv.w;
          av[si] += wv4.x * xv.x + wv4.y * xv.y + wv4.z * xv.z + wv4.w * xv.w;
        }
      }
    }
    const float bkk = p.bk[k], bvv = p.bv[k];
#pragma unroll
    for (int si = 0; si < 13; ++si) {
      const int s = sg + si * 16;
      if (s < NS) {
        const size_t o = ((size_t)bb * NS + s) * NK + k;
        p.keys[o] = ak[si] + bkk;
        p.values[o] = av[si] + bvv;
      }
    }
  }
  grid.sync();

  // ================= decode loop =================
  for (int step = 0; step < NT; ++step) {
    const int cur = step & 1;
    const float* h0c = p.h0t + cur * 16384;
    float* h0n = p.h0t + (cur ^ 1) * 16384;
    const float* h1c = p.h1t + cur * 16384;
    float* h1n = p.h1t + (cur ^ 1) * 16384;

    // ---------- phase 1: LSTM0 (rows = 4 gates x 512 d; block owns d-pair) ----------
    if (t < 32) {
      u64 m = p.amax[t];
#pragma unroll
      for (int s2 = 1; s2 < 8; ++s2) { const u64 o = p.amax[s2 * 32 + t]; if (o > m) m = o; }
      tok_lds[t] = (int)(0xFFFFFFFFu - (unsigned)(m & 0xFFFFFFFFull));
    }
    __syncthreads();
    {
      // stage emb rows (k4 0..127): thread (eb = t>>4, sl = t&15)
      const int eb = t >> 4, sl = t & 15;
      const float* er = p.emb + (size_t)tok_lds[eb] * ND;
#pragma unroll
      for (int j = 0; j < 12; ++j) {
        const int k4 = sl + j * 16;
        *(float4*)(lds + 4 * swz4(eb, k4, 192)) = *(const float4*)(er + k4 * 4);
      }
      // stage ctx (k4 128..191): read float4 over b, 4 scalar swizzled writes
      const int b4 = (t & 7) * 4, ck0 = t >> 3;
#pragma unroll
      for (int j = 0; j < 4; ++j) {
        const int ck = ck0 + j * 64;
        const float4 v = *(const float4*)(p.ctx + (size_t)ck * 32 + b4);
        const int k4 = 128 + (ck >> 2), comp = ck & 3;
        lds[4 * swz4(b4 + 0, k4, 192) + comp] = v.x;
        lds[4 * swz4(b4 + 1, k4, 192) + comp] = v.y;
        lds[4 * swz4(b4 + 2, k4, 192) + comp] = v.z;
        lds[4 * swz4(b4 + 3, k4, 192) + comp] = v.w;
      }
    }
    __syncthreads();
    {
      const int g = w & 3, kh = w >> 2;
      const int b = lane & 31, kq = lane >> 5;
      const int r0 = g * ND + bid * 2, r1 = r0 + 1;
      float a0 = 0.f, a1 = 0.f;
      // ih part (768) from LDS: 48 k4 per lane
      const int k40 = kh * 96 + kq * 48;
      const float* wi0 = p.Wih0 + (size_t)r0 * 768;
      const float* wi1 = p.Wih0 + (size_t)r1 * 768;
#pragma unroll 4
      for (int j = 0; j < 48; ++j) {
        const int k4 = k40 + j;
        const float4 in4 = *(const float4*)(lds + 4 * swz4(b, k4, 192));
        const float4 w0 = *(const float4*)(wi0 + k4 * 4);
        const float4 w1 = *(const float4*)(wi1 + k4 * 4);
        a0 += w0.x * in4.x + w0.y * in4.y + w0.z * in4.z + w0.w * in4.w;
        a1 += w1.x * in4.x + w1.y * in4.y + w1.z * in4.z + w1.w * in4.w;
      }
      // hh part (512) from global transposed h0c
      const int kb = kh * 256 + kq * 128;
      const float* wh0 = p.Whh0 + (size_t)r0 * ND;
      const float* wh1 = p.Whh0 + (size_t)r1 * ND;
#pragma unroll 2
      for (int j4 = 0; j4 < 32; ++j4) {
        const int k = kb + j4 * 4;
        const float4 w0 = *(const float4*)(wh0 + k);
        const float4 w1 = *(const float4*)(wh1 + k);
        const float hv0 = h0c[(k + 0) * 32 + b];
        const float hv1 = h0c[(k + 1) * 32 + b];
        const float hv2 = h0c[(k + 2) * 32 + b];
        const float hv3 = h0c[(k + 3) * 32 + b];
        a0 += w0.x * hv0 + w0.y * hv1 + w0.z * hv2 + w0.w * hv3;
        a1 += w1.x * hv0 + w1.y * hv1 + w1.z * hv2 + w1.w * hv3;
      }
      a0 += __shfl_xor(a0, 32);
      a1 += __shfl_xor(a1, 32);
      if (kq == 0) { gp[kh][g][0][b] = a0; gp[kh][g][1][b] = a1; }
    }
    __syncthreads();
    if (t < 64) {
      const int dl = t >> 5, b = t & 31;
      const int d = bid * 2 + dl;
      float gg[4];
#pragma unroll
      for (int g2 = 0; g2 < 4; ++g2)
        gg[g2] = gp[0][g2][dl][b] + gp[1][g2][dl][b] + p.bih0[g2 * ND + d] + p.bhh0[g2 * ND + d];
      const int idx = d * 32 + b;
      const float cn = sigm(gg[1]) * p.c0[idx] + sigm(gg[0]) * tanhf(gg[2]);
      p.c0[idx] = cn;
      h0n[idx] = sigm(gg[3]) * tanhf(cn);
    }
    grid.sync();

    // ---------- phase 2: LSTM1 (+ amax reset by block 0) ----------
    if (bid == 0 && t < 256) p.amax[t] = 0ull;
    {
      // stage h0n (k4 0..127) and h1c (k4 128..255) into lds [32][1024]
      const int b4 = (t & 7) * 4, kk = t >> 3;
#pragma unroll
      for (int j = 0; j < 8; ++j) {
        const int k = kk + j * 64;
        const float4 v0 = *(const float4*)(h0n + (size_t)k * 32 + b4);
        const float4 v1 = *(const float4*)(h1c + (size_t)k * 32 + b4);
        const int k4 = k >> 2, comp = k & 3;
        lds[4 * swz4(b4 + 0, k4, 256) + comp] = v0.x;
        lds[4 * swz4(b4 + 1, k4, 256) + comp] = v0.y;
        lds[4 * swz4(b4 + 2, k4, 256) + comp] = v0.z;
        lds[4 * swz4(b4 + 3, k4, 256) + comp] = v0.w;
        lds[4 * swz4(b4 + 0, 128 + k4, 256) + comp] = v1.x;
        lds[4 * swz4(b4 + 1, 128 + k4, 256) + comp] = v1.y;
        lds[4 * swz4(b4 + 2, 128 + k4, 256) + comp] = v1.z;
        lds[4 * swz4(b4 + 3, 128 + k4, 256) + comp] = v1.w;
      }
    }
    __syncthreads();
    {
      const int g = w & 3, kh = w >> 2;
      const int b = lane & 31, kq = lane >> 5;
      const int r0 = g * ND + bid * 2, r1 = r0 + 1;
      float a0 = 0.f, a1 = 0.f;
      // kh=0 -> Wih1 over h0n half; kh=1 -> Whh1 over h1c half (clean split)
      const int k40 = kh * 128 + kq * 64;
      const float* base0 = (kh == 0 ? p.Wih1 : p.Whh1) + (size_t)r0 * ND + kq * 256;
      const float* base1 = (kh == 0 ? p.Wih1 : p.Whh1) + (size_t)r1 * ND + kq * 256;
#pragma unroll 4
      for (int j = 0; j < 64; ++j) {
        const float4 in4 = *(const float4*)(lds + 4 * swz4(b, k40 + j, 256));
        const float4 w0 = *(const float4*)(base0 + j * 4);
        const float4 w1 = *(const float4*)(base1 + j * 4);
        a0 += w0.x * in4.x + w0.y * in4.y + w0.z * in4.z + w0.w * in4.w;
        a1 += w1.x * in4.x + w1.y * in4.y + w1.z * in4.z + w1.w * in4.w;
      }
      a0 += __shfl_xor(a0, 32);
      a1 += __shfl_xor(a1, 32);
      if (kq == 0) { gp[kh][g][0][b] = a0; gp[kh][g][1][b] = a1; }
    }
    __syncthreads();
    if (t < 64) {
      const int dl = t >> 5, b = t & 31;
      const int d = bid * 2 + dl;
      float gg[4];
#pragma unroll
      for (int g2 = 0; g2 < 4; ++g2)
        gg[g2] = gp[0][g2][dl][b] + gp[1][g2][dl][b] + p.bih1[g2 * ND + d] + p.bhh1[g2 * ND + d];
      const int idx = d * 32 + b;
      const float cn = sigm(gg[1]) * p.c1[idx] + sigm(gg[0]) * tanhf(gg[2]);
      p.c1[idx] = cn;
      h1n[idx] = sigm(gg[3]) * tanhf(cn);
    }
    grid.sync();

    // ---------- phase 3: attention (blocks 0..31, block = batch b) ----------
    if (bid < 32) {
      const int b = bid;
      attb[t] = h1n[(size_t)t * 32 + b];
      __syncthreads();
      const int kl = lane & 31, rh = lane >> 5;
      // q = Wq @ h1 + bq, scaled
      for (int pp = 0; pp < 16; ++pp) {
        const int r = w * 32 + pp * 2 + rh;
        const float* wq = p.Wq + (size_t)r * ND + kl * 4;
        float a = 0.f;
#pragma unroll
        for (int i = 0; i < 4; ++i) {
          const float4 w4 = *(const float4*)(wq + i * 128);
          const float4 p4 = *(const float4*)(attb + i * 128 + kl * 4);
          a += w4.x * p4.x + w4.y * p4.y + w4.z * p4.z + w4.w * p4.w;
        }
#pragma unroll
        for (int mk = 1; mk < 32; mk <<= 1) a += __shfl_xor(a, mk);
        if (kl == 0) attq[r] = (a + p.bq[r]) * 0.0625f;
      }
      __syncthreads();
      // energy over 196 keys
      for (int pp = 0; pp < 13; ++pp) {
        const int s = pp * 16 + w * 2 + rh;
        float a = 0.f;
        if (s < NS) {
          const float* kr = p.keys + ((size_t)b * NS + s) * NK + kl * 4;
#pragma unroll
          for (int i = 0; i < 2; ++i) {
            const float4 k4 = *(const float4*)(kr + i * 128);
            const float4 q4 = *(const float4*)(attq + i * 128 + kl * 4);
            a += k4.x * q4.x + k4.y * q4.y + k4.z * q4.z + k4.w * q4.w;
          }
        }
#pragma unroll
        for (int mk = 1; mk < 32; mk <<= 1) a += __shfl_xor(a, mk);
        if (kl == 0 && s < NS) smx[s] = a;
      }
      __syncthreads();
      // softmax
      float e = -INFINITY;
      if (t < 256) { e = (t < NS) ? smx[t] : -INFINITY; red[t] = e; }
      __syncthreads();
      for (int off = 128; off; off >>= 1) {
        if (t < off) red[t] = fmaxf(red[t], red[t + off]);
        __syncthreads();
      }
      const float mx = red[0];
      __syncthreads();
      float a = 0.f;
      if (t < 256) { a = (t < NS) ? expf(e - mx) : 0.f; red[t] = a; }
      __syncthreads();
      for (int off = 128; off; off >>= 1) {
        if (t < off) red[t] += red[t + off];
        __syncthreads();
      }
      const float inv = 1.0f / red[0];
      if (t < 256) smx[t] = a * inv;
      __syncthreads();
      // ctx
      if (t < 256) {
        const float* vb = p.values + (size_t)b * NS * NK + t;
        float c0_ = 0.f, c1_ = 0.f, c2_ = 0.f, c3_ = 0.f;
        for (int s = 0; s < NS; s += 4) {
          c0_ += smx[s + 0] * vb[(size_t)(s + 0) * NK];
          c1_ += smx[s + 1] * vb[(size_t)(s + 1) * NK];
          c2_ += smx[s + 2] * vb[(size_t)(s + 2) * NK];
          c3_ += smx[s + 3] * vb[(size_t)(s + 3) * NK];
        }
        p.ctx[(size_t)t * 32 + b] = (c0_ + c1_) + (c2_ + c3_);
      }
    }
    grid.sync();

    // ---------- phase 4: pred GEMM (blocks 0..249, 40 vocab rows each) ----------
    if (bid < 250) {
      {
        // stage h1n (k4 0..127) + ctx (k4 128..191) into lds [32][768]
        const int b4 = (t & 7) * 4, kk = t >> 3;
#pragma unroll
        for (int j = 0; j < 8; ++j) {
          const int k = kk + j * 64;
          const float4 v = *(const float4*)(h1n + (size_t)k * 32 + b4);
          const int k4 = k >> 2, comp = k & 3;
          lds[4 * swz4(b4 + 0, k4, 192) + comp] = v.x;
          lds[4 * swz4(b4 + 1, k4, 192) + comp] = v.y;
          lds[4 * swz4(b4 + 2, k4, 192) + comp] = v.z;
          lds[4 * swz4(b4 + 3, k4, 192) + comp] = v.w;
        }
#pragma unroll
        for (int j = 0; j < 4; ++j) {
          const int ck = kk + j * 64;
          const float4 v = *(const float4*)(p.ctx + (size_t)ck * 32 + b4);
          const int k4 = 128 + (ck >> 2), comp = ck & 3;
          lds[4 * swz4(b4 + 0, k4, 192) + comp] = v.x;
          lds[4 * swz4(b4 + 1, k4, 192) + comp] = v.y;
          lds[4 * swz4(b4 + 2, k4, 192) + comp] = v.z;
          lds[4 * swz4(b4 + 3, k4, 192) + comp] = v.w;
        }
      }
      __syncthreads();
      const int b = lane & 31, kh = lane >> 5;
      const int rbase = bid * 40 + w * 5;
      const float* wr0 = p.Wp + (size_t)(rbase + 0) * 768 + kh * 384;
      const float* wr1 = p.Wp + (size_t)(rbase + 1) * 768 + kh * 384;
      const float* wr2 = p.Wp + (size_t)(rbase + 2) * 768 + kh * 384;
      const float* wr3 = p.Wp + (size_t)(rbase + 3) * 768 + kh * 384;
      const float* wr4 = p.Wp + (size_t)(rbase + 4) * 768 + kh * 384;
      float acc0 = 0.f, acc1 = 0.f, acc2 = 0.f, acc3 = 0.f, acc4 = 0.f;
      const int k40 = kh * 96;
#pragma unroll 2
      for (int j = 0; j < 96; ++j) {
        const float4 in4 = *(const float4*)(lds + 4 * swz4(b, k40 + j, 192));
        const float4 w0 = *(const float4*)(wr0 + j * 4);
        const float4 w1 = *(const float4*)(wr1 + j * 4);
        const float4 w2 = *(const float4*)(wr2 + j * 4);
        const float4 w3 = *(const float4*)(wr3 + j * 4);
        const float4 w4 = *(const float4*)(wr4 + j * 4);
        acc0 += w0.x * in4.x + w0.y * in4.y + w0.z * in4.z + w0.w * in4.w;
        acc1 += w1.x * in4.x + w1.y * in4.y + w1.z * in4.z + w1.w * in4.w;
        acc2 += w2.x * in4.x + w2.y * in4.y + w2.z * in4.z + w2.w * in4.w;
        acc3 += w3.x * in4.x + w3.y * in4.y + w3.z * in4.z + w3.w * in4.w;
        acc4 += w4.x * in4.x + w4.y * in4.y + w4.z * in4.z + w4.w * in4.w;
      }
      acc0 += __shfl_xor(acc0, 32);
      acc1 += __shfl_xor(acc1, 32);
      acc2 += __shfl_xor(acc2, 32);
      acc3 += __shfl_xor(acc3, 32);
      acc4 += __shfl_xor(acc4, 32);
      if (kh == 0) {
        const size_t ro = ((size_t)b * NT + step) * NV + rbase;
        float v0 = acc0 + p.bp[rbase + 0];
        float v1 = acc1 + p.bp[rbase + 1];
        float v2 = acc2 + p.bp[rbase + 2];
        float v3 = acc3 + p.bp[rbase + 3];
        float v4 = acc4 + p.bp[rbase + 4];
        p.out[ro + 0] = v0; p.out[ro + 1] = v1; p.out[ro + 2] = v2;
        p.out[ro + 3] = v3; p.out[ro + 4] = v4;
        u64 m = packmax(v0, rbase + 0);
        u64 o1 = packmax(v1, rbase + 1); if (o1 > m) m = o1;
        u64 o2 = packmax(v2, rbase + 2); if (o2 > m) m = o2;
        u64 o3 = packmax(v3, rbase + 3); if (o3 > m) m = o3;
        u64 o4 = packmax(v4, rbase + 4); if (o4 > m) m = o4;
        cand[w][b] = m;
      }
      __syncthreads();
      if (t < 32) {
        u64 mm = cand[0][t];
#pragma unroll
        for (int i = 1; i < 8; ++i) { const u64 o = cand[i][t]; if (o > mm) mm = o; }
        atomicMax(&p.amax[(bid & 7) * 32 + t], mm);
      }
    }
    grid.sync();
  }
}

// ---------------- host ----------------
extern "C" void kernel_launch(void* const* d_in, const int* in_sizes, int n_in,
                              void* d_out, int out_size, void* d_ws, size_t ws_size,
                              hipStream_t stream) {
  (void)in_sizes; (void)n_in; (void)out_size; (void)ws_size;
  Params prm;
  prm.x    = (const float*)d_in[0];
  prm.emb  = (const float*)d_in[1];
  prm.Wk   = (const float*)d_in[2];
  prm.bk   = (const float*)d_in[3];
  prm.Wv   = (const float*)d_in[4];
  prm.bv   = (const float*)d_in[5];
  prm.Wq   = (const float*)d_in[6];
  prm.bq   = (const float*)d_in[7];
  prm.Wp   = (const float*)d_in[8];
  prm.bp   = (const float*)d_in[9];
  prm.Wih0 = (const float*)d_in[10];
  prm.Whh0 = (const float*)d_in[11];
  prm.bih0 = (const float*)d_in[12];
  prm.bhh0 = (const float*)d_in[13];
  prm.Wih1 = (const float*)d_in[14];
  prm.Whh1 = (const float*)d_in[15];
  prm.bih1 = (const float*)d_in[16];
  prm.bhh1 = (const float*)d_in[17];
  prm.out  = (float*)d_out;

  float* ws = (float*)d_ws;
  prm.keys   = ws;                         // 32*196*256 = 1,605,632
  prm.values = prm.keys + 1605632;         // 1,605,632
  prm.h0t    = prm.values + 1605632;       // [2][512*32] = 32,768
  prm.h1t    = prm.h0t + 32768;            // 32,768
  prm.c0     = prm.h1t + 32768;            // 16,384
  prm.c1     = prm.c0 + 16384;             // 16,384
  prm.ctx    = prm.c1 + 16384;             // [256][32] = 8,192
  prm.amax   = (u64*)(prm.ctx + 8192);     // [8][32] packed argmax slots

  const int LDS = 32 * 1024 * 4;           // 131,072 B dynamic (lstm1 layout)
  (void)hipFuncSetAttribute((const void*)k_all, hipFuncAttributeMaxDynamicSharedMemorySize, LDS);
  void* args[] = { &prm };
  (void)hipLaunchCooperativeKernel((const void*)k_all, dim3(NBLK), dim3(NTHR), args,
                                   (unsigned)LDS, stream);
}

// Round 4
// 72105.048 us; speedup vs baseline: 1.1124x; 1.1124x over previous
//
#include <hip/hip_runtime.h>
#include <hip/hip_cooperative_groups.h>
#include <math.h>

// RNNAttentionDecoder on MI355X — round 4: persistent cooperative kernel,
// conflict-free LDS staging (proven bijective bank mapping), LSTM0 weights
// pinned in LDS, all activations row-major [b][k], 4-row register-blocked
// LSTM waves. All f32 (argmax feedback forbids bf16; no fp32 MFMA on CDNA4).

namespace cg = cooperative_groups;
typedef unsigned long long u64;

#define NS 196
#define ND 512
#define NK 256
#define NV 10000
#define NT 300
#define NBLK 256
#define NTHR 512

__device__ __forceinline__ float sigm(float x) { return 1.0f / (1.0f + expf(-x)); }

// monotone f32 -> u32, packed with (0xFFFFFFFF - v): max() = (max value, smallest idx)
__device__ __forceinline__ u64 packmax(float x, int v) {
  unsigned u = __float_as_uint(x);
  u = (u & 0x80000000u) ? ~u : (u | 0x80000000u);
  return ((u64)u << 32) | (u64)(0xFFFFFFFFu - (unsigned)v);
}

// Swizzled float4-slot for staged activations, row stride 160 slots.
// granule%8 = (k4^b)&7: bijective over b (reads: fixed k4, b=0..7 per phase)
// and over sl (writes: fixed b, k4 low bits 0..7 per phase) -> conflict-free.
__device__ __forceinline__ int slotOf(int b, int k4) {
  return b * 160 + ((k4 & ~7) | ((k4 ^ b) & 7));
}

struct Params {
  const float *x, *emb, *Wk, *bk, *Wv, *bv, *Wq, *bq, *Wp, *bp;
  const float *Wih0, *Whh0, *bih0, *bhh0, *Wih1, *Whh1, *bih1, *bhh1;
  float *out, *keys, *values, *h0t, *h1t, *c0, *c1, *ctx;
  u64 *amax;
};

__global__ __launch_bounds__(NTHR, 2) void k_all(Params p) {
  cg::grid_group grid = cg::this_grid();
  extern __shared__ float dyn[];
  float* W0lds = dyn;            // [8][1280] = 10240 floats (40 KB), persistent
  float* stage = dyn + 10240;    // [32][160] float4-slots = 20480 floats (80 KB)

  __shared__ int tok_lds[32];
  __shared__ float gp[4][8][32];   // [k-quarter][row][b]
  __shared__ float gsum[8][32];
  __shared__ float attq[256];
  __shared__ float attb[512];
  __shared__ float red[256];
  __shared__ float smx[256];
  __shared__ u64 cand[8][32];

  const int bid = blockIdx.x;
  const int t = threadIdx.x;
  const int lane = t & 63;
  const int w = t >> 6;

  // ---------------- init: zero states (row-major [b][k]), seed argmax ----------------
  {
    const int g = bid * NTHR + t;
    if (g < 106496) p.h0t[g] = 0.0f;  // h0t[2],h1t[2],c0,c1,ctx contiguous
    if (g < 256) p.amax[g] = (g < 32) ? ((1ull << 32) | 0xFFFFFFFFull) : 0ull;
  }

  // ---------------- pin LSTM0 weights in LDS: W0[r][0:768]=Wih0, [768:1280]=Whh0 ----------------
  {
    const int r = t >> 6, ln = t & 63;
    const int g = r >> 1, dl = r & 1;
    const float* src_ih = p.Wih0 + (size_t)(g * ND + bid * 2 + dl) * 768;
    const float* src_hh = p.Whh0 + (size_t)(g * ND + bid * 2 + dl) * ND;
#pragma unroll
    for (int j = 0; j < 5; ++j) {
      const int col = 4 * (ln + 64 * j);   // 0..1276
      const float4 v = (col < 768) ? *(const float4*)(src_ih + col)
                                   : *(const float4*)(src_hh + (col - 768));
      *(float4*)(W0lds + r * 1280 + col) = v;
    }
  }

  // ---------------- keys/values (once): block = (k-chunk, b) ----------------
  {
    const int kc = bid & 7, bb = bid >> 3;
    const int kl = t & 31, sg = t >> 5;  // sg 0..15
    const int k = kc * 32 + kl;
    float ak[13], av[13];
#pragma unroll
    for (int i = 0; i < 13; ++i) { ak[i] = 0.f; av[i] = 0.f; }
    const float* wkr = p.Wk + (size_t)k * ND;
    const float* wvr = p.Wv + (size_t)k * ND;
    const float* xb = p.x + (size_t)bb * NS * ND;
    for (int j = 0; j < ND; j += 4) {
      const float4 wk4 = *(const float4*)(wkr + j);
      const float4 wv4 = *(const float4*)(wvr + j);
#pragma unroll
      for (int si = 0; si < 13; ++si) {
        const int s = sg + si * 16;
        if (s < NS) {
          const float4 xv = *(const float4*)(xb + (size_t)s * ND + j);
          ak[si] += wk4.x * xv.x + wk4.y * xv.y + wk4.z * xv.z + wk4.w * xv.w;
          av[si] += wv4.x * xv.x + wv4.y * xv.y + wv4.z * xv.z + wv4.w * xv.w;
        }
      }
    }
    const float bkk = p.bk[k], bvv = p.bv[k];
#pragma unroll
    for (int si = 0; si < 13; ++si) {
      const int s = sg + si * 16;
      if (s < NS) {
        const size_t o = ((size_t)bb * NS + s) * NK + k;
        p.keys[o] = ak[si] + bkk;
        p.values[o] = av[si] + bvv;
      }
    }
  }
  grid.sync();

  // ---------------- decode loop ----------------
  for (int step = 0; step < NT; ++step) {
    const int cur = step & 1;
    const float* h0c = p.h0t + cur * 16384;
    float* h0n = p.h0t + (cur ^ 1) * 16384;
    const float* h1c = p.h1t + cur * 16384;
    float* h1n = p.h1t + (cur ^ 1) * 16384;

    // ========== phase 1: LSTM0 (8 rows/block; wave = (row-group, k-quarter)) ==========
    if (t < 32) {
      u64 m = p.amax[t];
#pragma unroll
      for (int s2 = 1; s2 < 8; ++s2) { const u64 o = p.amax[s2 * 32 + t]; if (o > m) m = o; }
      tok_lds[t] = (int)(0xFFFFFFFFu - (unsigned)(m & 0xFFFFFFFFull));
    }
    __syncthreads();
    {
      const int rq = w >> 2, ks = w & 3;
      const int b = lane & 31, kqq = lane >> 5;
      const int rb = rq * 4;
      float a0 = 0.f, a1 = 0.f, a2 = 0.f, a3 = 0.f;
      for (int c = 0; c < 2; ++c) {
        // stage chunk c of concat [emb(512)|ctx(256)|h0(512)] -> [32][160 k4]
        {
          const int sb = t >> 4, sl = t & 15;
#pragma unroll
          for (int j = 0; j < 10; ++j) {
            const int k4 = sl + 16 * j;
            const float* src;
            if (c == 0) {
              src = (k4 < 128) ? (p.emb + (size_t)tok_lds[sb] * ND + 4 * k4)
                               : (p.ctx + sb * NK + (4 * k4 - 512));
            } else {
              src = (k4 < 32) ? (p.ctx + sb * NK + 128 + 4 * k4)
                              : (h0c + sb * ND + (4 * k4 - 128));
            }
            *(float4*)(stage + 4 * slotOf(sb, k4)) = *(const float4*)src;
          }
        }
        __syncthreads();
        const int k4b = ks * 40 + kqq * 20;
        const float* w0 = W0lds + (rb + 0) * 1280 + c * 640;
        const float* w1 = W0lds + (rb + 1) * 1280 + c * 640;
        const float* w2 = W0lds + (rb + 2) * 1280 + c * 640;
        const float* w3 = W0lds + (rb + 3) * 1280 + c * 640;
#pragma unroll 5
        for (int j = 0; j < 20; ++j) {
          const int k4 = k4b + j;
          const float4 a4 = *(const float4*)(stage + 4 * slotOf(b, k4));
          const int wi = 4 * k4;
          const float4 q0 = *(const float4*)(w0 + wi);
          const float4 q1 = *(const float4*)(w1 + wi);
          const float4 q2 = *(const float4*)(w2 + wi);
          const float4 q3 = *(const float4*)(w3 + wi);
          a0 += q0.x * a4.x + q0.y * a4.y + q0.z * a4.z + q0.w * a4.w;
          a1 += q1.x * a4.x + q1.y * a4.y + q1.z * a4.z + q1.w * a4.w;
          a2 += q2.x * a4.x + q2.y * a4.y + q2.z * a4.z + q2.w * a4.w;
          a3 += q3.x * a4.x + q3.y * a4.y + q3.z * a4.z + q3.w * a4.w;
        }
        __syncthreads();
      }
      a0 += __shfl_xor(a0, 32);
      a1 += __shfl_xor(a1, 32);
      a2 += __shfl_xor(a2, 32);
      a3 += __shfl_xor(a3, 32);
      if (kqq == 0) {
        gp[ks][rb + 0][b] = a0; gp[ks][rb + 1][b] = a1;
        gp[ks][rb + 2][b] = a2; gp[ks][rb + 3][b] = a3;
      }
    }
    __syncthreads();
    if (t < 256) {
      const int r = t >> 5, b2 = t & 31;
      const int grow = (r >> 1) * ND + bid * 2 + (r & 1);
      gsum[r][b2] = gp[0][r][b2] + gp[1][r][b2] + gp[2][r][b2] + gp[3][r][b2]
                  + p.bih0[grow] + p.bhh0[grow];
    }
    __syncthreads();
    if (t < 64) {
      const int dl = t >> 5, b2 = t & 31;
      const int d = bid * 2 + dl;
      const float gi = gsum[0 + dl][b2], gf = gsum[2 + dl][b2];
      const float gg = gsum[4 + dl][b2], go = gsum[6 + dl][b2];
      const int idx = b2 * ND + d;
      const float cn = sigm(gf) * p.c0[idx] + sigm(gi) * tanhf(gg);
      p.c0[idx] = cn;
      h0n[idx] = sigm(go) * tanhf(cn);
    }
    grid.sync();

    // ========== phase 2: LSTM1 (weights streamed, L2-pinned) + amax reset ==========
    if (bid == 0 && t < 256) p.amax[t] = 0ull;
    {
      const int rq = w >> 2, ks = w & 3;
      const int b = lane & 31, kqq = lane >> 5;
      const int rb = rq * 4;
      float a0 = 0.f, a1 = 0.f, a2 = 0.f, a3 = 0.f;
      for (int c = 0; c < 2; ++c) {
        {
          const int sb = t >> 4, sl = t & 15;
          const float* hsrc = (c == 0) ? h0n : h1c;
#pragma unroll
          for (int j = 0; j < 8; ++j) {
            const int k4 = sl + 16 * j;   // < 128
            *(float4*)(stage + 4 * slotOf(sb, k4)) =
                *(const float4*)(hsrc + sb * ND + 4 * k4);
          }
        }
        __syncthreads();
        const int k4b = ks * 32 + kqq * 16;
        const float* wb = (c == 0) ? p.Wih1 : p.Whh1;
        const int rg0 = ((rb + 0) >> 1) * ND + bid * 2 + ((rb + 0) & 1);
        const int rg1 = ((rb + 1) >> 1) * ND + bid * 2 + ((rb + 1) & 1);
        const int rg2 = ((rb + 2) >> 1) * ND + bid * 2 + ((rb + 2) & 1);
        const int rg3 = ((rb + 3) >> 1) * ND + bid * 2 + ((rb + 3) & 1);
        const float* w0 = wb + (size_t)rg0 * ND;
        const float* w1 = wb + (size_t)rg1 * ND;
        const float* w2 = wb + (size_t)rg2 * ND;
        const float* w3 = wb + (size_t)rg3 * ND;
#pragma unroll 4
        for (int j = 0; j < 16; ++j) {
          const int k4 = k4b + j;
          const float4 a4 = *(const float4*)(stage + 4 * slotOf(b, k4));
          const int wi = 4 * k4;
          const float4 q0 = *(const float4*)(w0 + wi);
          const float4 q1 = *(const float4*)(w1 + wi);
          const float4 q2 = *(const float4*)(w2 + wi);
          const float4 q3 = *(const float4*)(w3 + wi);
          a0 += q0.x * a4.x + q0.y * a4.y + q0.z * a4.z + q0.w * a4.w;
          a1 += q1.x * a4.x + q1.y * a4.y + q1.z * a4.z + q1.w * a4.w;
          a2 += q2.x * a4.x + q2.y * a4.y + q2.z * a4.z + q2.w * a4.w;
          a3 += q3.x * a4.x + q3.y * a4.y + q3.z * a4.z + q3.w * a4.w;
        }
        __syncthreads();
      }
      a0 += __shfl_xor(a0, 32);
      a1 += __shfl_xor(a1, 32);
      a2 += __shfl_xor(a2, 32);
      a3 += __shfl_xor(a3, 32);
      if (kqq == 0) {
        gp[ks][rb + 0][b] = a0; gp[ks][rb + 1][b] = a1;
        gp[ks][rb + 2][b] = a2; gp[ks][rb + 3][b] = a3;
      }
    }
    __syncthreads();
    if (t < 256) {
      const int r = t >> 5, b2 = t & 31;
      const int grow = (r >> 1) * ND + bid * 2 + (r & 1);
      gsum[r][b2] = gp[0][r][b2] + gp[1][r][b2] + gp[2][r][b2] + gp[3][r][b2]
                  + p.bih1[grow] + p.bhh1[grow];
    }
    __syncthreads();
    if (t < 64) {
      const int dl = t >> 5, b2 = t & 31;
      const int d = bid * 2 + dl;
      const float gi = gsum[0 + dl][b2], gf = gsum[2 + dl][b2];
      const float gg = gsum[4 + dl][b2], go = gsum[6 + dl][b2];
      const int idx = b2 * ND + d;
      const float cn = sigm(gf) * p.c1[idx] + sigm(gi) * tanhf(gg);
      p.c1[idx] = cn;
      h1n[idx] = sigm(go) * tanhf(cn);
    }
    grid.sync();

    // ========== phase 3: attention (blocks 0..31, block = batch b) ==========
    if (bid < 32) {
      const int b = bid;
      attb[t] = h1n[(size_t)b * ND + t];   // coalesced row-major read
      __syncthreads();
      const int kl = lane & 31, rh = lane >> 5;
      for (int pp = 0; pp < 16; ++pp) {
        const int r = w * 32 + pp * 2 + rh;
        const float* wq = p.Wq + (size_t)r * ND + kl * 4;
        float a = 0.f;
#pragma unroll
        for (int i = 0; i < 4; ++i) {
          const float4 w4 = *(const float4*)(wq + i * 128);
          const float4 p4 = *(const float4*)(attb + i * 128 + kl * 4);
          a += w4.x * p4.x + w4.y * p4.y + w4.z * p4.z + w4.w * p4.w;
        }
#pragma unroll
        for (int mk = 1; mk < 32; mk <<= 1) a += __shfl_xor(a, mk);
        if (kl == 0) attq[r] = (a + p.bq[r]) * 0.0625f;   // 1/sqrt(256)
      }
      __syncthreads();
      for (int pp = 0; pp < 13; ++pp) {
        const int s = pp * 16 + w * 2 + rh;
        float a = 0.f;
        if (s < NS) {
          const float* kr = p.keys + ((size_t)b * NS + s) * NK + kl * 4;
#pragma unroll
          for (int i = 0; i < 2; ++i) {
            const float4 k4 = *(const float4*)(kr + i * 128);
            const float4 q4 = *(const float4*)(attq + i * 128 + kl * 4);
            a += k4.x * q4.x + k4.y * q4.y + k4.z * q4.z + k4.w * q4.w;
          }
        }
#pragma unroll
        for (int mk = 1; mk < 32; mk <<= 1) a += __shfl_xor(a, mk);
        if (kl == 0 && s < NS) smx[s] = a;
      }
      __syncthreads();
      float e = -INFINITY;
      if (t < 256) { e = (t < NS) ? smx[t] : -INFINITY; red[t] = e; }
      __syncthreads();
      for (int off = 128; off; off >>= 1) {
        if (t < off) red[t] = fmaxf(red[t], red[t + off]);
        __syncthreads();
      }
      const float mx = red[0];
      __syncthreads();
      float a = 0.f;
      if (t < 256) { a = (t < NS) ? expf(e - mx) : 0.f; red[t] = a; }
      __syncthreads();
      for (int off = 128; off; off >>= 1) {
        if (t < off) red[t] += red[t + off];
        __syncthreads();
      }
      const float inv = 1.0f / red[0];
      if (t < 256) smx[t] = a * inv;
      __syncthreads();
      if (t < 256) {
        const float* vb = p.values + (size_t)b * NS * NK + t;
        float c0_ = 0.f, c1_ = 0.f, c2_ = 0.f, c3_ = 0.f;
        for (int s = 0; s < NS; s += 4) {
          c0_ += smx[s + 0] * vb[(size_t)(s + 0) * NK];
          c1_ += smx[s + 1] * vb[(size_t)(s + 1) * NK];
          c2_ += smx[s + 2] * vb[(size_t)(s + 2) * NK];
          c3_ += smx[s + 3] * vb[(size_t)(s + 3) * NK];
        }
        p.ctx[b * NK + t] = (c0_ + c1_) + (c2_ + c3_);   // coalesced row-major write
      }
    }
    grid.sync();

    // ========== phase 4: pred GEMM (blocks 0..249, 40 rows; wave = 5 rows) ==========
    if (bid < 250) {
      const int b = lane & 31, kqq = lane >> 5;
      const int rbase = bid * 40 + w * 5;
      const float* wr0 = p.Wp + (size_t)(rbase + 0) * 768;
      const float* wr1 = p.Wp + (size_t)(rbase + 1) * 768;
      const float* wr2 = p.Wp + (size_t)(rbase + 2) * 768;
      const float* wr3 = p.Wp + (size_t)(rbase + 3) * 768;
      const float* wr4 = p.Wp + (size_t)(rbase + 4) * 768;
      float acc0 = 0.f, acc1 = 0.f, acc2 = 0.f, acc3 = 0.f, acc4 = 0.f;
      for (int h = 0; h < 2; ++h) {
        {
          const int sb = t >> 4, sl = t & 15;
#pragma unroll
          for (int j = 0; j < 6; ++j) {
            const int k4 = sl + 16 * j;   // < 96
            const int col = h * 384 + 4 * k4;
            const float* src = (col < 512) ? (h1n + sb * ND + col)
                                           : (p.ctx + sb * NK + (col - 512));
            *(float4*)(stage + 4 * slotOf(sb, k4)) = *(const float4*)src;
          }
        }
        __syncthreads();
#pragma unroll 4
        for (int j = 0; j < 48; ++j) {
          const int k4 = kqq * 48 + j;
          const float4 a4 = *(const float4*)(stage + 4 * slotOf(b, k4));
          const int wcol = h * 384 + 4 * k4;
          const float4 q0 = *(const float4*)(wr0 + wcol);
          const float4 q1 = *(const float4*)(wr1 + wcol);
          const float4 q2 = *(const float4*)(wr2 + wcol);
          const float4 q3 = *(const float4*)(wr3 + wcol);
          const float4 q4 = *(const float4*)(wr4 + wcol);
          acc0 += q0.x * a4.x + q0.y * a4.y + q0.z * a4.z + q0.w * a4.w;
          acc1 += q1.x * a4.x + q1.y * a4.y + q1.z * a4.z + q1.w * a4.w;
          acc2 += q2.x * a4.x + q2.y * a4.y + q2.z * a4.z + q2.w * a4.w;
          acc3 += q3.x * a4.x + q3.y * a4.y + q3.z * a4.z + q3.w * a4.w;
          acc4 += q4.x * a4.x + q4.y * a4.y + q4.z * a4.z + q4.w * a4.w;
        }
        __syncthreads();
      }
      acc0 += __shfl_xor(acc0, 32);
      acc1 += __shfl_xor(acc1, 32);
      acc2 += __shfl_xor(acc2, 32);
      acc3 += __shfl_xor(acc3, 32);
      acc4 += __shfl_xor(acc4, 32);
      if (kqq == 0) {
        const size_t ro = ((size_t)b * NT + step) * NV + rbase;
        const float v0 = acc0 + p.bp[rbase + 0];
        const float v1 = acc1 + p.bp[rbase + 1];
        const float v2 = acc2 + p.bp[rbase + 2];
        const float v3 = acc3 + p.bp[rbase + 3];
        const float v4 = acc4 + p.bp[rbase + 4];
        p.out[ro + 0] = v0; p.out[ro + 1] = v1; p.out[ro + 2] = v2;
        p.out[ro + 3] = v3; p.out[ro + 4] = v4;
        u64 m = packmax(v0, rbase + 0);
        u64 o1 = packmax(v1, rbase + 1); if (o1 > m) m = o1;
        u64 o2 = packmax(v2, rbase + 2); if (o2 > m) m = o2;
        u64 o3 = packmax(v3, rbase + 3); if (o3 > m) m = o3;
        u64 o4 = packmax(v4, rbase + 4); if (o4 > m) m = o4;
        cand[w][b] = m;
      }
      __syncthreads();
      if (t < 32) {
        u64 mm = cand[0][t];
#pragma unroll
        for (int i = 1; i < 8; ++i) { const u64 o = cand[i][t]; if (o > mm) mm = o; }
        atomicMax(&p.amax[(bid & 7) * 32 + t], mm);
      }
    }
    grid.sync();
  }
}

// ---------------- host ----------------
extern "C" void kernel_launch(void* const* d_in, const int* in_sizes, int n_in,
                              void* d_out, int out_size, void* d_ws, size_t ws_size,
                              hipStream_t stream) {
  (void)in_sizes; (void)n_in; (void)out_size; (void)ws_size;
  Params prm;
  prm.x    = (const float*)d_in[0];
  prm.emb  = (const float*)d_in[1];
  prm.Wk   = (const float*)d_in[2];
  prm.bk   = (const float*)d_in[3];
  prm.Wv   = (const float*)d_in[4];
  prm.bv   = (const float*)d_in[5];
  prm.Wq   = (const float*)d_in[6];
  prm.bq   = (const float*)d_in[7];
  prm.Wp   = (const float*)d_in[8];
  prm.bp   = (const float*)d_in[9];
  prm.Wih0 = (const float*)d_in[10];
  prm.Whh0 = (const float*)d_in[11];
  prm.bih0 = (const float*)d_in[12];
  prm.bhh0 = (const float*)d_in[13];
  prm.Wih1 = (const float*)d_in[14];
  prm.Whh1 = (const float*)d_in[15];
  prm.bih1 = (const float*)d_in[16];
  prm.bhh1 = (const float*)d_in[17];
  prm.out  = (float*)d_out;

  float* ws = (float*)d_ws;
  prm.keys   = ws;                         // 32*196*256 = 1,605,632
  prm.values = prm.keys + 1605632;         // 1,605,632
  prm.h0t    = prm.values + 1605632;       // [2][32][512] = 32,768  (zeroed from here)
  prm.h1t    = prm.h0t + 32768;            // 32,768
  prm.c0     = prm.h1t + 32768;            // 16,384
  prm.c1     = prm.c0 + 16384;             // 16,384
  prm.ctx    = prm.c1 + 16384;             // [32][256] = 8,192
  prm.amax   = (u64*)(prm.ctx + 8192);     // [8][32] packed argmax slots

  const int LDS = (10240 + 20480) * 4;     // 122,880 B dynamic
  (void)hipFuncSetAttribute((const void*)k_all, hipFuncAttributeMaxDynamicSharedMemorySize, LDS);
  void* args[] = { &prm };
  (void)hipLaunchCooperativeKernel((const void*)k_all, dim3(NBLK), dim3(NTHR), args,
                                   (unsigned)LDS, stream);
}

// Round 5
// 55139.362 us; speedup vs baseline: 1.4547x; 1.3077x over previous
//
#include <hip/hip_runtime.h>
#include <math.h>

// RNNAttentionDecoder on MI355X — round 5: persistent cooperative kernel with
// CUSTOM hierarchical grid barrier (replaces cg::grid.sync ~50µs with ~2µs),
// Wp pinned in LDS per block (kills 30.7 MB/step streaming), activations
// transposed [k][32b] for direct coalesced reads, Q as its own phase.
// All f32 (argmax feedback forbids bf16; no fp32 MFMA on CDNA4).

typedef unsigned long long u64;

#define NS 196
#define ND 512
#define NK 256
#define NV 10000
#define NT 300
#define NBLK 256
#define NTHR 512

__device__ __forceinline__ float sigm(float x) { return 1.0f / (1.0f + expf(-x)); }

// monotone f32 -> u32, packed with (0xFFFFFFFF - v): max() = (max value, smallest idx)
__device__ __forceinline__ u64 packmax(float x, int v) {
  unsigned u = __float_as_uint(x);
  u = (u & 0x80000000u) ? ~u : (u | 0x80000000u);
  return ((u64)u << 32) | (u64)(0xFFFFFFFFu - (unsigned)v);
}

// swizzled f4-slot for emb stage [32 rows][32 f4]: granule (k4^b)&7
__device__ __forceinline__ int eslot(int b, int k4) {
  return b * 32 + ((k4 & ~7) | ((k4 ^ b) & 7));
}

// ---- custom monotonic hierarchical grid barrier ----
// bar[g*32]        : group arrival counters (32 groups of 8 blocks, 128B apart)
// bar[1024+g*32]   : group release flags
// bar[2048]        : root counter
// Monotonic epochs; state zeroed by k_zbar before each launch (graph-safe).
__device__ __forceinline__ void gbar(unsigned* bar, int bid, unsigned ep) {
  __syncthreads();
  if (threadIdx.x == 0) {
    __threadfence();
    const int g = bid & 31;
    const unsigned old =
        __hip_atomic_fetch_add(&bar[g * 32], 1u, __ATOMIC_ACQ_REL, __HIP_MEMORY_SCOPE_AGENT);
    if (old == ep * 8u - 1u) {  // last of this group
      const unsigned r =
          __hip_atomic_fetch_add(&bar[2048], 1u, __ATOMIC_ACQ_REL, __HIP_MEMORY_SCOPE_AGENT);
      if (r == ep * 32u - 1u) {  // last overall: release all groups
#pragma unroll
        for (int i = 0; i < 32; ++i)
          __hip_atomic_store(&bar[1024 + i * 32], ep, __ATOMIC_RELEASE, __HIP_MEMORY_SCOPE_AGENT);
      }
    }
    while (__hip_atomic_load(&bar[1024 + g * 32], __ATOMIC_RELAXED, __HIP_MEMORY_SCOPE_AGENT) < ep)
      __builtin_amdgcn_s_sleep(1);
    __threadfence();
  }
  __syncthreads();
}

__global__ __launch_bounds__(256) void k_zbar(unsigned* bar) {
  const int i = blockIdx.x * 256 + threadIdx.x;
  if (i < 2112) bar[i] = 0u;
}

struct Params {
  const float *x, *emb, *Wk, *bk, *Wv, *bv, *Wq, *bq, *Wp, *bp;
  const float *Wih0, *Whh0, *bih0, *bhh0, *Wih1, *Whh1, *bih1, *bhh1;
  float *out, *keys, *values, *h0t, *h1t, *c0, *c1, *ctx, *qg;
  u64 *amax;
  unsigned *bar;
};

__global__ __launch_bounds__(NTHR, 1) void k_all(Params p) {
  extern __shared__ float dyn[];
  float* Wp_lds = dyn;          // [40][768] = 30720 floats (120 KB)
  float* stage = dyn + 30720;   // [32][32] f4-slots = 4096 floats (16 KB)

  __shared__ int tok_lds[32];
  __shared__ float gp[4][8][32];
  __shared__ float gsum[8][32];
  __shared__ __align__(16) float attq[256];
  __shared__ float attb[512];
  __shared__ float red[256];
  __shared__ float smx[256];
  __shared__ u64 cand[8][32];

  const int bid = blockIdx.x;
  const int t = threadIdx.x;
  const int lane = t & 63;
  const int w = t >> 6;

  // ---------------- init: zero states, seed argmax (tok=0) ----------------
  {
    const int g = bid * NTHR + t;
    if (g < 106496) p.h0t[g] = 0.0f;  // h0t[2],h1t[2],c0,c1,ctx contiguous
    if (g < 256) p.amax[g] = (g < 32) ? ((1ull << 32) | 0xFFFFFFFFull) : 0ull;
  }

  // ---------------- pin Wp slice in LDS (once) ----------------
  if (bid < 250) {
    const float* src = p.Wp + (size_t)bid * 40 * 768;
    for (int i = t; i < 7680; i += NTHR)
      *(float4*)(Wp_lds + 4 * i) = *(const float4*)(src + 4 * i);
  }

  // ---------------- keys/values (once): block = (k-chunk, b) ----------------
  {
    const int kc = bid & 7, bb = bid >> 3;
    const int kl = t & 31, sg = t >> 5;  // sg 0..15
    const int k = kc * 32 + kl;
    float ak[13], av[13];
#pragma unroll
    for (int i = 0; i < 13; ++i) { ak[i] = 0.f; av[i] = 0.f; }
    const float* wkr = p.Wk + (size_t)k * ND;
    const float* wvr = p.Wv + (size_t)k * ND;
    const float* xb = p.x + (size_t)bb * NS * ND;
    for (int j = 0; j < ND; j += 4) {
      const float4 wk4 = *(const float4*)(wkr + j);
      const float4 wv4 = *(const float4*)(wvr + j);
#pragma unroll
      for (int si = 0; si < 13; ++si) {
        const int s = sg + si * 16;
        if (s < NS) {
          const float4 xv = *(const float4*)(xb + (size_t)s * ND + j);
          ak[si] += wk4.x * xv.x + wk4.y * xv.y + wk4.z * xv.z + wk4.w * xv.w;
          av[si] += wv4.x * xv.x + wv4.y * xv.y + wv4.z * xv.z + wv4.w * xv.w;
        }
      }
    }
    const float bkk = p.bk[k], bvv = p.bv[k];
#pragma unroll
    for (int si = 0; si < 13; ++si) {
      const int s = sg + si * 16;
      if (s < NS) {
        const size_t o = ((size_t)bb * NS + s) * NK + k;
        p.keys[o] = ak[si] + bkk;
        p.values[o] = av[si] + bvv;
      }
    }
  }
  unsigned ep = 1;
  gbar(p.bar, bid, ep++);

  // ---------------- decode loop ----------------
  for (int step = 0; step < NT; ++step) {
    const int cur = step & 1;
    const float* h0c = p.h0t + cur * 16384;
    float* h0n = p.h0t + (cur ^ 1) * 16384;
    const float* h1c = p.h1t + cur * 16384;
    float* h1n = p.h1t + (cur ^ 1) * 16384;

    // ===== P1: LSTM0. 8 gate-rows/block; wave=(row-quad, k-slice); acts transposed =====
    if (t < 32) {
      u64 m = p.amax[t];
#pragma unroll
      for (int s2 = 1; s2 < 8; ++s2) { const u64 o = p.amax[s2 * 32 + t]; if (o > m) m = o; }
      tok_lds[t] = (int)(0xFFFFFFFFu - (unsigned)(m & 0xFFFFFFFFull));
    }
    __syncthreads();
    {
      const int rq = w >> 2, ks = w & 3;
      const int b = lane & 31, kq = lane >> 5;
      const int s = ks * 2 + kq;        // k-slice 0..7
      const int rb = rq * 4;
      int rg[4];
#pragma unroll
      for (int i = 0; i < 4; ++i)
        rg[i] = ((rb + i) >> 1) * ND + bid * 2 + ((rb + i) & 1);
      float a0 = 0.f, a1 = 0.f, a2 = 0.f, a3 = 0.f;
      // emb part: 4 staged chunks of 32 f4
      for (int c = 0; c < 4; ++c) {
        {
          const int sb = t >> 4, sl = t & 15;
          const float* er = p.emb + (size_t)tok_lds[sb] * ND + c * 128;
          *(float4*)(stage + 4 * eslot(sb, sl)) = *(const float4*)(er + 4 * sl);
          *(float4*)(stage + 4 * eslot(sb, sl + 16)) = *(const float4*)(er + 4 * (sl + 16));
        }
        __syncthreads();
        const int j0 = s * 4;
#pragma unroll
        for (int jj = 0; jj < 4; ++jj) {
          const int k4 = j0 + jj;
          const float4 a4 = *(const float4*)(stage + 4 * eslot(b, k4));
          const int wc = (c * 32 + k4) * 4;
          const float4 q0 = *(const float4*)(p.Wih0 + (size_t)rg[0] * 768 + wc);
          const float4 q1 = *(const float4*)(p.Wih0 + (size_t)rg[1] * 768 + wc);
          const float4 q2 = *(const float4*)(p.Wih0 + (size_t)rg[2] * 768 + wc);
          const float4 q3 = *(const float4*)(p.Wih0 + (size_t)rg[3] * 768 + wc);
          a0 += q0.x * a4.x + q0.y * a4.y + q0.z * a4.z + q0.w * a4.w;
          a1 += q1.x * a4.x + q1.y * a4.y + q1.z * a4.z + q1.w * a4.w;
          a2 += q2.x * a4.x + q2.y * a4.y + q2.z * a4.z + q2.w * a4.w;
          a3 += q3.x * a4.x + q3.y * a4.y + q3.z * a4.z + q3.w * a4.w;
        }
        __syncthreads();
      }
      // ctx part: k4 in [8s, 8s+8), weight cols 512+4k4 (transposed-global acts)
#pragma unroll 4
      for (int j = 0; j < 8; ++j) {
        const int kf = (s * 8 + j) * 4;
        const float x0 = p.ctx[(kf + 0) * 32 + b];
        const float x1 = p.ctx[(kf + 1) * 32 + b];
        const float x2 = p.ctx[(kf + 2) * 32 + b];
        const float x3 = p.ctx[(kf + 3) * 32 + b];
        const int wc = 512 + kf;
        const float4 q0 = *(const float4*)(p.Wih0 + (size_t)rg[0] * 768 + wc);
        const float4 q1 = *(const float4*)(p.Wih0 + (size_t)rg[1] * 768 + wc);
        const float4 q2 = *(const float4*)(p.Wih0 + (size_t)rg[2] * 768 + wc);
        const float4 q3 = *(const float4*)(p.Wih0 + (size_t)rg[3] * 768 + wc);
        a0 += q0.x * x0 + q0.y * x1 + q0.z * x2 + q0.w * x3;
        a1 += q1.x * x0 + q1.y * x1 + q1.z * x2 + q1.w * x3;
        a2 += q2.x * x0 + q2.y * x1 + q2.z * x2 + q2.w * x3;
        a3 += q3.x * x0 + q3.y * x1 + q3.z * x2 + q3.w * x3;
      }
      // h0 part: k4 in [16s, 16s+16), Whh0 cols 4k4
#pragma unroll 4
      for (int j = 0; j < 16; ++j) {
        const int kf = (s * 16 + j) * 4;
        const float x0 = h0c[(kf + 0) * 32 + b];
        const float x1 = h0c[(kf + 1) * 32 + b];
        const float x2 = h0c[(kf + 2) * 32 + b];
        const float x3 = h0c[(kf + 3) * 32 + b];
        const float4 q0 = *(const float4*)(p.Whh0 + (size_t)rg[0] * ND + kf);
        const float4 q1 = *(const float4*)(p.Whh0 + (size_t)rg[1] * ND + kf);
        const float4 q2 = *(const float4*)(p.Whh0 + (size_t)rg[2] * ND + kf);
        const float4 q3 = *(const float4*)(p.Whh0 + (size_t)rg[3] * ND + kf);
        a0 += q0.x * x0 + q0.y * x1 + q0.z * x2 + q0.w * x3;
        a1 += q1.x * x0 + q1.y * x1 + q1.z * x2 + q1.w * x3;
        a2 += q2.x * x0 + q2.y * x1 + q2.z * x2 + q2.w * x3;
        a3 += q3.x * x0 + q3.y * x1 + q3.z * x2 + q3.w * x3;
      }
      a0 += __shfl_xor(a0, 32);
      a1 += __shfl_xor(a1, 32);
      a2 += __shfl_xor(a2, 32);
      a3 += __shfl_xor(a3, 32);
      if (kq == 0) {
        gp[ks][rb + 0][b] = a0; gp[ks][rb + 1][b] = a1;
        gp[ks][rb + 2][b] = a2; gp[ks][rb + 3][b] = a3;
      }
    }
    __syncthreads();
    if (t < 256) {
      const int r = t >> 5, b2 = t & 31;
      const int grow = (r >> 1) * ND + bid * 2 + (r & 1);
      gsum[r][b2] = gp[0][r][b2] + gp[1][r][b2] + gp[2][r][b2] + gp[3][r][b2]
                  + p.bih0[grow] + p.bhh0[grow];
    }
    __syncthreads();
    if (t < 64) {
      const int dl = t >> 5, b2 = t & 31;
      const int d = bid * 2 + dl;
      const float gi = gsum[0 + dl][b2], gf = gsum[2 + dl][b2];
      const float gg = gsum[4 + dl][b2], go = gsum[6 + dl][b2];
      const int idx = d * 32 + b2;
      const float cn = sigm(gf) * p.c0[idx] + sigm(gi) * tanhf(gg);
      p.c0[idx] = cn;
      h0n[idx] = sigm(go) * tanhf(cn);
    }
    gbar(p.bar, bid, ep++);

    // ===== P2: LSTM1 (+ amax reset by block 0) =====
    if (bid == 0 && t < 256) p.amax[t] = 0ull;
    {
      const int rq = w >> 2, ks = w & 3;
      const int b = lane & 31, kq = lane >> 5;
      const int s = ks * 2 + kq;
      const int rb = rq * 4;
      int rg[4];
#pragma unroll
      for (int i = 0; i < 4; ++i)
        rg[i] = ((rb + i) >> 1) * ND + bid * 2 + ((rb + i) & 1);
      float a0 = 0.f, a1 = 0.f, a2 = 0.f, a3 = 0.f;
#pragma unroll 4
      for (int j = 0; j < 16; ++j) {
        const int kf = (s * 16 + j) * 4;
        const float x0 = h0n[(kf + 0) * 32 + b];
        const float x1 = h0n[(kf + 1) * 32 + b];
        const float x2 = h0n[(kf + 2) * 32 + b];
        const float x3 = h0n[(kf + 3) * 32 + b];
        const float4 q0 = *(const float4*)(p.Wih1 + (size_t)rg[0] * ND + kf);
        const float4 q1 = *(const float4*)(p.Wih1 + (size_t)rg[1] * ND + kf);
        const float4 q2 = *(const float4*)(p.Wih1 + (size_t)rg[2] * ND + kf);
        const float4 q3 = *(const float4*)(p.Wih1 + (size_t)rg[3] * ND + kf);
        a0 += q0.x * x0 + q0.y * x1 + q0.z * x2 + q0.w * x3;
        a1 += q1.x * x0 + q1.y * x1 + q1.z * x2 + q1.w * x3;
        a2 += q2.x * x0 + q2.y * x1 + q2.z * x2 + q2.w * x3;
        a3 += q3.x * x0 + q3.y * x1 + q3.z * x2 + q3.w * x3;
      }
#pragma unroll 4
      for (int j = 0; j < 16; ++j) {
        const int kf = (s * 16 + j) * 4;
        const float x0 = h1c[(kf + 0) * 32 + b];
        const float x1 = h1c[(kf + 1) * 32 + b];
        const float x2 = h1c[(kf + 2) * 32 + b];
        const float x3 = h1c[(kf + 3) * 32 + b];
        const float4 q0 = *(const float4*)(p.Whh1 + (size_t)rg[0] * ND + kf);
        const float4 q1 = *(const float4*)(p.Whh1 + (size_t)rg[1] * ND + kf);
        const float4 q2 = *(const float4*)(p.Whh1 + (size_t)rg[2] * ND + kf);
        const float4 q3 = *(const float4*)(p.Whh1 + (size_t)rg[3] * ND + kf);
        a0 += q0.x * x0 + q0.y * x1 + q0.z * x2 + q0.w * x3;
        a1 += q1.x * x0 + q1.y * x1 + q1.z * x2 + q1.w * x3;
        a2 += q2.x * x0 + q2.y * x1 + q2.z * x2 + q2.w * x3;
        a3 += q3.x * x0 + q3.y * x1 + q3.z * x2 + q3.w * x3;
      }
      a0 += __shfl_xor(a0, 32);
      a1 += __shfl_xor(a1, 32);
      a2 += __shfl_xor(a2, 32);
      a3 += __shfl_xor(a3, 32);
      if (kq == 0) {
        gp[ks][rb + 0][b] = a0; gp[ks][rb + 1][b] = a1;
        gp[ks][rb + 2][b] = a2; gp[ks][rb + 3][b] = a3;
      }
    }
    __syncthreads();
    if (t < 256) {
      const int r = t >> 5, b2 = t & 31;
      const int grow = (r >> 1) * ND + bid * 2 + (r & 1);
      gsum[r][b2] = gp[0][r][b2] + gp[1][r][b2] + gp[2][r][b2] + gp[3][r][b2]
                  + p.bih1[grow] + p.bhh1[grow];
    }
    __syncthreads();
    if (t < 64) {
      const int dl = t >> 5, b2 = t & 31;
      const int d = bid * 2 + dl;
      const float gi = gsum[0 + dl][b2], gf = gsum[2 + dl][b2];
      const float gg = gsum[4 + dl][b2], go = gsum[6 + dl][b2];
      const int idx = d * 32 + b2;
      const float cn = sigm(gf) * p.c1[idx] + sigm(gi) * tanhf(gg);
      p.c1[idx] = cn;
      h1n[idx] = sigm(go) * tanhf(cn);
    }
    gbar(p.bar, bid, ep++);

    // ===== P3: Q projection. block = q-row r (256 rows); threads (k-slice, b) =====
    {
      const int r = bid;
      const int b = t & 31, sl = t >> 5;  // 16 k-slices of 32
      const float* wq = p.Wq + (size_t)r * ND + sl * 32;
      float acc = 0.f;
#pragma unroll 8
      for (int kk = 0; kk < 32; ++kk)
        acc += wq[kk] * h1n[(sl * 32 + kk) * 32 + b];
      attb[t] = acc;
      __syncthreads();
      if (t < 32) {
        float q = 0.f;
#pragma unroll
        for (int i = 0; i < 16; ++i) q += attb[i * 32 + t];
        p.qg[r * 32 + t] = (q + p.bq[r]) * 0.0625f;  // 1/sqrt(256)
      }
    }
    gbar(p.bar, bid, ep++);

    // ===== P4: attention (blocks 0..31, block = batch b) =====
    if (bid < 32) {
      const int b = bid;
      if (t < 256) attq[t] = p.qg[t * 32 + b];
      __syncthreads();
      const int kl = lane & 31, rh = lane >> 5;
      // energies over 196 keys
      for (int pp = 0; pp < 13; ++pp) {
        const int s = pp * 16 + w * 2 + rh;
        float a = 0.f;
        if (s < NS) {
          const float* kr = p.keys + ((size_t)b * NS + s) * NK + kl * 4;
#pragma unroll
          for (int i = 0; i < 2; ++i) {
            const float4 k4 = *(const float4*)(kr + i * 128);
            const float4 q4 = *(const float4*)(attq + i * 128 + kl * 4);
            a += k4.x * q4.x + k4.y * q4.y + k4.z * q4.z + k4.w * q4.w;
          }
        }
#pragma unroll
        for (int mk = 1; mk < 32; mk <<= 1) a += __shfl_xor(a, mk);
        if (kl == 0 && s < NS) smx[s] = a;
      }
      __syncthreads();
      float e = -INFINITY;
      if (t < 256) { e = (t < NS) ? smx[t] : -INFINITY; red[t] = e; }
      __syncthreads();
      for (int off = 128; off; off >>= 1) {
        if (t < off) red[t] = fmaxf(red[t], red[t + off]);
        __syncthreads();
      }
      const float mx = red[0];
      __syncthreads();
      float a = 0.f;
      if (t < 256) { a = (t < NS) ? expf(e - mx) : 0.f; red[t] = a; }
      __syncthreads();
      for (int off = 128; off; off >>= 1) {
        if (t < off) red[t] += red[t + off];
        __syncthreads();
      }
      const float inv = 1.0f / red[0];
      if (t < 256) smx[t] = a * inv;
      __syncthreads();
      if (t < 256) {
        const float* vb = p.values + (size_t)b * NS * NK + t;
        float c0_ = 0.f, c1_ = 0.f, c2_ = 0.f, c3_ = 0.f;
        for (int s = 0; s < NS; s += 4) {
          c0_ += smx[s + 0] * vb[(size_t)(s + 0) * NK];
          c1_ += smx[s + 1] * vb[(size_t)(s + 1) * NK];
          c2_ += smx[s + 2] * vb[(size_t)(s + 2) * NK];
          c3_ += smx[s + 3] * vb[(size_t)(s + 3) * NK];
        }
        p.ctx[t * 32 + b] = (c0_ + c1_) + (c2_ + c3_);  // transposed [k][b]
      }
    }
    gbar(p.bar, bid, ep++);

    // ===== P5: pred GEMV from LDS-pinned Wp. wave=5 rows; lane=(kq,16b); 2 b/lane =====
    if (bid < 250) {
      const int bh = lane & 15, kq = lane >> 4;  // 4 k-slices interleaved
      const int rloc = w * 5;
      const int rbase = bid * 40 + rloc;
      float acc[5][2];
#pragma unroll
      for (int r = 0; r < 5; ++r) { acc[r][0] = 0.f; acc[r][1] = 0.f; }
#pragma unroll 2
      for (int j = 0; j < 48; ++j) {
        const int k4 = j * 4 + kq;     // bank-clean interleave
        const int kf = k4 * 4;
        float x0[2], x1[2], x2[2], x3[2];
        {
          const float* s0 = (kf + 0 < 512) ? (h1n + (kf + 0) * 32) : (p.ctx + (kf + 0 - 512) * 32);
          const float* s1 = (kf + 1 < 512) ? (h1n + (kf + 1) * 32) : (p.ctx + (kf + 1 - 512) * 32);
          const float* s2 = (kf + 2 < 512) ? (h1n + (kf + 2) * 32) : (p.ctx + (kf + 2 - 512) * 32);
          const float* s3 = (kf + 3 < 512) ? (h1n + (kf + 3) * 32) : (p.ctx + (kf + 3 - 512) * 32);
          x0[0] = s0[bh]; x0[1] = s0[bh + 16];
          x1[0] = s1[bh]; x1[1] = s1[bh + 16];
          x2[0] = s2[bh]; x2[1] = s2[bh + 16];
          x3[0] = s3[bh]; x3[1] = s3[bh + 16];
        }
#pragma unroll
        for (int r = 0; r < 5; ++r) {
          const float4 w4 = *(const float4*)(Wp_lds + (rloc + r) * 768 + kf);
          acc[r][0] += w4.x * x0[0] + w4.y * x1[0] + w4.z * x2[0] + w4.w * x3[0];
          acc[r][1] += w4.x * x0[1] + w4.y * x1[1] + w4.z * x2[1] + w4.w * x3[1];
        }
      }
#pragma unroll
      for (int r = 0; r < 5; ++r) {
#pragma unroll
        for (int u = 0; u < 2; ++u) {
          acc[r][u] += __shfl_xor(acc[r][u], 16);
          acc[r][u] += __shfl_xor(acc[r][u], 32);
        }
      }
      if (kq == 0) {
#pragma unroll
        for (int u = 0; u < 2; ++u) {
          const int b = bh + u * 16;
          const size_t ro = ((size_t)b * NT + step) * NV + rbase;
          u64 m = 0ull;
#pragma unroll
          for (int r = 0; r < 5; ++r) {
            const float v = acc[r][u] + p.bp[rbase + r];
            p.out[ro + r] = v;
            const u64 pk = packmax(v, rbase + r);
            if (pk > m) m = pk;
          }
          cand[w][b] = m;
        }
      }
      __syncthreads();
      if (t < 32) {
        u64 mm = cand[0][t];
#pragma unroll
        for (int i = 1; i < 8; ++i) { const u64 o = cand[i][t]; if (o > mm) mm = o; }
        atomicMax(&p.amax[(bid & 7) * 32 + t], mm);
      }
    }
    gbar(p.bar, bid, ep++);
  }
}

// ---------------- host ----------------
extern "C" void kernel_launch(void* const* d_in, const int* in_sizes, int n_in,
                              void* d_out, int out_size, void* d_ws, size_t ws_size,
                              hipStream_t stream) {
  (void)in_sizes; (void)n_in; (void)out_size; (void)ws_size;
  Params prm;
  prm.x    = (const float*)d_in[0];
  prm.emb  = (const float*)d_in[1];
  prm.Wk   = (const float*)d_in[2];
  prm.bk   = (const float*)d_in[3];
  prm.Wv   = (const float*)d_in[4];
  prm.bv   = (const float*)d_in[5];
  prm.Wq   = (const float*)d_in[6];
  prm.bq   = (const float*)d_in[7];
  prm.Wp   = (const float*)d_in[8];
  prm.bp   = (const float*)d_in[9];
  prm.Wih0 = (const float*)d_in[10];
  prm.Whh0 = (const float*)d_in[11];
  prm.bih0 = (const float*)d_in[12];
  prm.bhh0 = (const float*)d_in[13];
  prm.Wih1 = (const float*)d_in[14];
  prm.Whh1 = (const float*)d_in[15];
  prm.bih1 = (const float*)d_in[16];
  prm.bhh1 = (const float*)d_in[17];
  prm.out  = (float*)d_out;

  float* ws = (float*)d_ws;
  prm.keys   = ws;                          // 1,605,632
  prm.values = prm.keys + 1605632;          // 1,605,632
  prm.h0t    = prm.values + 1605632;        // [2][512][32] = 32,768 (zero region start)
  prm.h1t    = prm.h0t + 32768;             // 32,768
  prm.c0     = prm.h1t + 32768;             // 16,384
  prm.c1     = prm.c0 + 16384;              // 16,384
  prm.ctx    = prm.c1 + 16384;              // [256][32] = 8,192
  prm.amax   = (u64*)(prm.ctx + 8192);      // 256 u64 = 512 f
  prm.qg     = prm.ctx + 8192 + 512;        // [256][32] = 8,192
  prm.bar    = (unsigned*)(prm.qg + 8192);  // 2,112 u32 barrier state

  const int LDS = (30720 + 4096) * 4;       // 139,264 B dynamic
  (void)hipFuncSetAttribute((const void*)k_all, hipFuncAttributeMaxDynamicSharedMemorySize, LDS);

  k_zbar<<<9, 256, 0, stream>>>(prm.bar);   // reset barrier state (graph-safe, deterministic)
  void* args[] = { &prm };
  (void)hipLaunchCooperativeKernel((const void*)k_all, dim3(NBLK), dim3(NTHR), args,
                                   (unsigned)LDS, stream);
}

// Round 6
// 39259.549 us; speedup vs baseline: 2.0430x; 1.4045x over previous
//
#include <hip/hip_runtime.h>
#include <math.h>

// RNNAttentionDecoder on MI355X — round 6: fence-free cross-XCD coherence.
// All mutable cross-block state goes through relaxed AGENT-scope atomics
// (per-access coherent, no buffer_wbl2/buffer_inv cache nukes); weights and
// keys/values stay L2-resident across all 300 steps. Custom hierarchical
// barrier with no fences (s_waitcnt vmcnt(0) + relaxed atomics + poll).
// Wp pinned in LDS; activations staged per-block through a 16KB swizzled
// LDS chunk buffer. All f32 (argmax feedback forbids bf16; no fp32 MFMA).

typedef unsigned long long u64;

#define NS 196
#define ND 512
#define NK 256
#define NV 10000
#define NT 300
#define NBLK 256
#define NTHR 512
#define SCOPE __HIP_MEMORY_SCOPE_AGENT

__device__ __forceinline__ float sigm(float x) { return 1.0f / (1.0f + expf(-x)); }

__device__ __forceinline__ float aldf(const float* p) {
  return __hip_atomic_load(p, __ATOMIC_RELAXED, SCOPE);
}
__device__ __forceinline__ void astf(float* p, float v) {
  __hip_atomic_store(p, v, __ATOMIC_RELAXED, SCOPE);
}
__device__ __forceinline__ u64 aldu(const u64* p) {
  return __hip_atomic_load(p, __ATOMIC_RELAXED, SCOPE);
}
__device__ __forceinline__ void astu(u64* p, u64 v) {
  __hip_atomic_store(p, v, __ATOMIC_RELAXED, SCOPE);
}

// monotone f32 -> u32, packed with (0xFFFFFFFF - v): max() = (max value, smallest idx)
__device__ __forceinline__ u64 packmax(float x, int v) {
  unsigned u = __float_as_uint(x);
  u = (u & 0x80000000u) ? ~u : (u | 0x80000000u);
  return ((u64)u << 32) | (u64)(0xFFFFFFFFu - (unsigned)v);
}

// swizzled f4-slot in the 16KB stage [32 rows][32 f4]: granule (k4^b)&7
__device__ __forceinline__ int eslot(int b, int k4) {
  return b * 32 + ((k4 & ~7) | ((k4 ^ b) & 7));
}

// ---- fence-free hierarchical grid barrier ----
// bar[g*32] g<8 : group arrival counters (XCD-aligned groups of 32 blocks)
// bar[256+g*32] : group release flags;  bar[512] : root counter
__device__ __forceinline__ void gbar(unsigned* bar, int bid, unsigned ep, bool fenced) {
  __syncthreads();
  if (threadIdx.x == 0) {
    if (fenced) __threadfence();
    asm volatile("s_waitcnt vmcnt(0)" ::: "memory");
    const int g = bid & 7;
    const unsigned old =
        __hip_atomic_fetch_add(&bar[g * 32], 1u, __ATOMIC_RELAXED, SCOPE);
    if (old == ep * 32u - 1u) {  // last of this group
      const unsigned r = __hip_atomic_fetch_add(&bar[512], 1u, __ATOMIC_RELAXED, SCOPE);
      if (r == ep * 8u - 1u) {   // last overall: release all groups
#pragma unroll
        for (int i = 0; i < 8; ++i)
          __hip_atomic_store(&bar[256 + i * 32], ep, __ATOMIC_RELAXED, SCOPE);
      }
    }
    while (__hip_atomic_load(&bar[256 + g * 32], __ATOMIC_RELAXED, SCOPE) < ep)
      __builtin_amdgcn_s_sleep(2);
    if (fenced) __threadfence();
  }
  __syncthreads();
}

__global__ __launch_bounds__(256) void k_zbar(unsigned* bar) {
  const int i = blockIdx.x * 256 + threadIdx.x;
  if (i < 1024) bar[i] = 0u;
}

struct Params {
  const float *x, *emb, *Wk, *bk, *Wv, *bv, *Wq, *bq, *Wp, *bp;
  const float *Wih0, *Whh0, *bih0, *bhh0, *Wih1, *Whh1, *bih1, *bhh1;
  float *out, *keys, *values, *h0t, *h1t, *c0, *c1, *ctx, *qg;
  u64 *amax;
  unsigned *bar;
};

__global__ __launch_bounds__(NTHR, 1) void k_all(Params p) {
  extern __shared__ float dyn[];
  float* Wp_lds = dyn;          // [40][768] = 30720 floats (120 KB), persistent
  float* stage  = dyn + 30720;  // [32][32] f4-slots = 4096 floats (16 KB)

  __shared__ int tok_lds[32];
  __shared__ float gp[4][8][32];   // [ks][row][b] partials (also reused by P3)
  __shared__ float gsum[8][32];
  __shared__ __align__(16) float attq[256];
  __shared__ float red[256];
  __shared__ float smx[256];
  __shared__ u64 cand[8][32];

  const int bid = blockIdx.x;
  const int t = threadIdx.x;
  const int lane = t & 63;
  const int w = t >> 6;

  // ---------------- init: zero state, seed argmax (tok=0) — all atomic ----------------
  {
    const int g = bid * NTHR + t;
    if (g < 106496) astf(&p.h0t[g], 0.0f);  // h0t[2],h1t[2],c0,c1,ctx contiguous
    if (g < 256) astu(&p.amax[g], (g < 32) ? ((1ull << 32) | 0xFFFFFFFFull) : 0ull);
  }

  // ---------------- pin Wp slice in LDS (once, cached reads) ----------------
  if (bid < 250) {
    const float* src = p.Wp + (size_t)bid * 40 * 768;
    for (int i = t; i < 7680; i += NTHR)
      *(float4*)(Wp_lds + 4 * i) = *(const float4*)(src + 4 * i);
  }

  // ---------------- keys/values (once): block = (k-chunk, b); plain stores ----------------
  {
    const int kc = bid & 7, bb = bid >> 3;
    const int kl = t & 31, sg = t >> 5;
    const int k = kc * 32 + kl;
    float ak[13], av[13];
#pragma unroll
    for (int i = 0; i < 13; ++i) { ak[i] = 0.f; av[i] = 0.f; }
    const float* wkr = p.Wk + (size_t)k * ND;
    const float* wvr = p.Wv + (size_t)k * ND;
    const float* xb = p.x + (size_t)bb * NS * ND;
    for (int j = 0; j < ND; j += 4) {
      const float4 wk4 = *(const float4*)(wkr + j);
      const float4 wv4 = *(const float4*)(wvr + j);
#pragma unroll
      for (int si = 0; si < 13; ++si) {
        const int s = sg + si * 16;
        if (s < NS) {
          const float4 xv = *(const float4*)(xb + (size_t)s * ND + j);
          ak[si] += wk4.x * xv.x + wk4.y * xv.y + wk4.z * xv.z + wk4.w * xv.w;
          av[si] += wv4.x * xv.x + wv4.y * xv.y + wv4.z * xv.z + wv4.w * xv.w;
        }
      }
    }
    const float bkk = p.bk[k], bvv = p.bv[k];
#pragma unroll
    for (int si = 0; si < 13; ++si) {
      const int s = sg + si * 16;
      if (s < NS) {
        const size_t o = ((size_t)bb * NS + s) * NK + k;
        p.keys[o] = ak[si] + bkk;
        p.values[o] = av[si] + bvv;
      }
    }
  }
  unsigned ep = 1;
  gbar(p.bar, bid, ep++, true);  // ONE fenced barrier: writes back dirty keys/values

  // ---------------- decode loop ----------------
  for (int step = 0; step < NT; ++step) {
    const int cur = step & 1;
    const float* h0c = p.h0t + cur * 16384;
    float* h0n = p.h0t + (cur ^ 1) * 16384;
    const float* h1c = p.h1t + cur * 16384;
    float* h1n = p.h1t + (cur ^ 1) * 16384;

    // ===== P1: LSTM0. 8 gate-rows/block; 10 staged chunks of 128 k =====
    if (t < 32) {
      u64 m = aldu(&p.amax[t]);
#pragma unroll
      for (int s2 = 1; s2 < 8; ++s2) { const u64 o = aldu(&p.amax[s2 * 32 + t]); if (o > m) m = o; }
      tok_lds[t] = (int)(0xFFFFFFFFu - (unsigned)(m & 0xFFFFFFFFull));
    }
    __syncthreads();
    {
      const int rq = w >> 2, ks = w & 3;
      const int b = lane & 31, kq = lane >> 5;
      const int rb = rq * 4;
      int rg[4];
#pragma unroll
      for (int i = 0; i < 4; ++i) rg[i] = ((rb + i) >> 1) * ND + bid * 2 + ((rb + i) & 1);
      float a0 = 0.f, a1 = 0.f, a2 = 0.f, a3 = 0.f;
      for (int c = 0; c < 10; ++c) {
        // ---- fill chunk c: k-global = [emb 0..511 | ctx 512..767 | h0 768..1279]
        if (c < 4) {
          const int eb = t >> 4, sl = t & 15;  // coalesced f4 rows from cached emb
          const float* er = p.emb + (size_t)tok_lds[eb] * ND + c * 128;
          *(float4*)(stage + 4 * eslot(eb, sl)) = *(const float4*)(er + 4 * sl);
          *(float4*)(stage + 4 * eslot(eb, sl + 16)) = *(const float4*)(er + 4 * (sl + 16));
        } else {
          float* srcm = (c < 6) ? (p.ctx + (c - 4) * 4096) : (float*)(h0c + (c - 6) * 4096);
          const int b2 = t & 31, kg = t >> 5;
#pragma unroll
          for (int kk = 0; kk < 8; ++kk) {
            const int k = kg * 8 + kk;
            stage[4 * eslot(b2, k >> 2) + (k & 3)] = aldf(srcm + k * 32 + b2);
          }
        }
        __syncthreads();
        // ---- compute: wave slice f4 = ks*8 + kq*4 + jj
        const float *wb0, *wb1, *wb2, *wb3;
        if (c < 6) {
          wb0 = p.Wih0 + (size_t)rg[0] * 768 + c * 128;
          wb1 = p.Wih0 + (size_t)rg[1] * 768 + c * 128;
          wb2 = p.Wih0 + (size_t)rg[2] * 768 + c * 128;
          wb3 = p.Wih0 + (size_t)rg[3] * 768 + c * 128;
        } else {
          wb0 = p.Whh0 + (size_t)rg[0] * ND + (c - 6) * 128;
          wb1 = p.Whh0 + (size_t)rg[1] * ND + (c - 6) * 128;
          wb2 = p.Whh0 + (size_t)rg[2] * ND + (c - 6) * 128;
          wb3 = p.Whh0 + (size_t)rg[3] * ND + (c - 6) * 128;
        }
#pragma unroll
        for (int jj = 0; jj < 4; ++jj) {
          const int f4 = ks * 8 + kq * 4 + jj;
          const float4 a4 = *(const float4*)(stage + 4 * eslot(b, f4));
          const float4 q0 = *(const float4*)(wb0 + 4 * f4);
          const float4 q1 = *(const float4*)(wb1 + 4 * f4);
          const float4 q2 = *(const float4*)(wb2 + 4 * f4);
          const float4 q3 = *(const float4*)(wb3 + 4 * f4);
          a0 += q0.x * a4.x + q0.y * a4.y + q0.z * a4.z + q0.w * a4.w;
          a1 += q1.x * a4.x + q1.y * a4.y + q1.z * a4.z + q1.w * a4.w;
          a2 += q2.x * a4.x + q2.y * a4.y + q2.z * a4.z + q2.w * a4.w;
          a3 += q3.x * a4.x + q3.y * a4.y + q3.z * a4.z + q3.w * a4.w;
        }
        __syncthreads();
      }
      a0 += __shfl_xor(a0, 32);
      a1 += __shfl_xor(a1, 32);
      a2 += __shfl_xor(a2, 32);
      a3 += __shfl_xor(a3, 32);
      if (kq == 0) {
        gp[ks][rb + 0][b] = a0; gp[ks][rb + 1][b] = a1;
        gp[ks][rb + 2][b] = a2; gp[ks][rb + 3][b] = a3;
      }
    }
    __syncthreads();
    if (t < 256) {
      const int r = t >> 5, b2 = t & 31;
      const int grow = (r >> 1) * ND + bid * 2 + (r & 1);
      gsum[r][b2] = gp[0][r][b2] + gp[1][r][b2] + gp[2][r][b2] + gp[3][r][b2]
                  + p.bih0[grow] + p.bhh0[grow];
    }
    __syncthreads();
    if (t < 64) {
      const int dl = t >> 5, b2 = t & 31;
      const int d = bid * 2 + dl;
      const float gi = gsum[0 + dl][b2], gf = gsum[2 + dl][b2];
      const float gg = gsum[4 + dl][b2], go = gsum[6 + dl][b2];
      const int idx = d * 32 + b2;
      const float cn = sigm(gf) * aldf(&p.c0[idx]) + sigm(gi) * tanhf(gg);
      astf(&p.c0[idx], cn);
      astf(&h0n[idx], sigm(go) * tanhf(cn));
    }
    gbar(p.bar, bid, ep++, false);

    // ===== P2: LSTM1 (8 staged chunks) + amax reset by block 0 =====
    if (bid == 0 && t < 256) astu(&p.amax[t], 0ull);
    {
      const int rq = w >> 2, ks = w & 3;
      const int b = lane & 31, kq = lane >> 5;
      const int rb = rq * 4;
      int rg[4];
#pragma unroll
      for (int i = 0; i < 4; ++i) rg[i] = ((rb + i) >> 1) * ND + bid * 2 + ((rb + i) & 1);
      float a0 = 0.f, a1 = 0.f, a2 = 0.f, a3 = 0.f;
      for (int c = 0; c < 8; ++c) {
        {
          const float* srcm = (c < 4) ? (h0n + c * 4096) : (h1c + (c - 4) * 4096);
          const int b2 = t & 31, kg = t >> 5;
#pragma unroll
          for (int kk = 0; kk < 8; ++kk) {
            const int k = kg * 8 + kk;
            stage[4 * eslot(b2, k >> 2) + (k & 3)] = aldf(srcm + k * 32 + b2);
          }
        }
        __syncthreads();
        const float* base = (c < 4) ? p.Wih1 : p.Whh1;
        const int coff = (c & 3) * 128;
        const float* wb0 = base + (size_t)rg[0] * ND + coff;
        const float* wb1 = base + (size_t)rg[1] * ND + coff;
        const float* wb2 = base + (size_t)rg[2] * ND + coff;
        const float* wb3 = base + (size_t)rg[3] * ND + coff;
#pragma unroll
        for (int jj = 0; jj < 4; ++jj) {
          const int f4 = ks * 8 + kq * 4 + jj;
          const float4 a4 = *(const float4*)(stage + 4 * eslot(b, f4));
          const float4 q0 = *(const float4*)(wb0 + 4 * f4);
          const float4 q1 = *(const float4*)(wb1 + 4 * f4);
          const float4 q2 = *(const float4*)(wb2 + 4 * f4);
          const float4 q3 = *(const float4*)(wb3 + 4 * f4);
          a0 += q0.x * a4.x + q0.y * a4.y + q0.z * a4.z + q0.w * a4.w;
          a1 += q1.x * a4.x + q1.y * a4.y + q1.z * a4.z + q1.w * a4.w;
          a2 += q2.x * a4.x + q2.y * a4.y + q2.z * a4.z + q2.w * a4.w;
          a3 += q3.x * a4.x + q3.y * a4.y + q3.z * a4.z + q3.w * a4.w;
        }
        __syncthreads();
      }
      a0 += __shfl_xor(a0, 32);
      a1 += __shfl_xor(a1, 32);
      a2 += __shfl_xor(a2, 32);
      a3 += __shfl_xor(a3, 32);
      if (kq == 0) {
        gp[ks][rb + 0][b] = a0; gp[ks][rb + 1][b] = a1;
        gp[ks][rb + 2][b] = a2; gp[ks][rb + 3][b] = a3;
      }
    }
    __syncthreads();
    if (t < 256) {
      const int r = t >> 5, b2 = t & 31;
      const int grow = (r >> 1) * ND + bid * 2 + (r & 1);
      gsum[r][b2] = gp[0][r][b2] + gp[1][r][b2] + gp[2][r][b2] + gp[3][r][b2]
                  + p.bih1[grow] + p.bhh1[grow];
    }
    __syncthreads();
    if (t < 64) {
      const int dl = t >> 5, b2 = t & 31;
      const int d = bid * 2 + dl;
      const float gi = gsum[0 + dl][b2], gf = gsum[2 + dl][b2];
      const float gg = gsum[4 + dl][b2], go = gsum[6 + dl][b2];
      const int idx = d * 32 + b2;
      const float cn = sigm(gf) * aldf(&p.c1[idx]) + sigm(gi) * tanhf(gg);
      astf(&p.c1[idx], cn);
      astf(&h1n[idx], sigm(go) * tanhf(cn));
    }
    gbar(p.bar, bid, ep++, false);

    // ===== P3: Q projection. 64 blocks x 4 rows; direct atomic reads of h1n =====
    if (bid < 64) {
      const int sl = t >> 5, b = t & 31;
      float acc0 = 0.f, acc1 = 0.f, acc2 = 0.f, acc3 = 0.f;
      const float* wq0 = p.Wq + (size_t)(bid * 4 + 0) * ND + sl * 32;
      const float* wq1 = p.Wq + (size_t)(bid * 4 + 1) * ND + sl * 32;
      const float* wq2 = p.Wq + (size_t)(bid * 4 + 2) * ND + sl * 32;
      const float* wq3 = p.Wq + (size_t)(bid * 4 + 3) * ND + sl * 32;
#pragma unroll 8
      for (int kk = 0; kk < 32; ++kk) {
        const float hv = aldf(h1n + (sl * 32 + kk) * 32 + b);
        acc0 += wq0[kk] * hv; acc1 += wq1[kk] * hv;
        acc2 += wq2[kk] * hv; acc3 += wq3[kk] * hv;
      }
      float* gpf = &gp[0][0][0];  // [16 sl][4 rl][32 b]
      gpf[(sl * 4 + 0) * 32 + b] = acc0;
      gpf[(sl * 4 + 1) * 32 + b] = acc1;
      gpf[(sl * 4 + 2) * 32 + b] = acc2;
      gpf[(sl * 4 + 3) * 32 + b] = acc3;
      __syncthreads();
      if (t < 128) {
        const int rl = t >> 5, b2 = t & 31;
        float q = 0.f;
#pragma unroll
        for (int s2 = 0; s2 < 16; ++s2) q += gpf[(s2 * 4 + rl) * 32 + b2];
        const int r = bid * 4 + rl;
        astf(&p.qg[r * 32 + b2], (q + p.bq[r]) * 0.0625f);  // 1/sqrt(256)
      }
    }
    gbar(p.bar, bid, ep++, false);

    // ===== P4: attention (blocks 0..31, block = batch b); keys/values L2-cached =====
    if (bid < 32) {
      const int b = bid;
      if (t < 256) attq[t] = aldf(&p.qg[t * 32 + b]);
      __syncthreads();
      const int kl = lane & 31, rh = lane >> 5;
      for (int pp = 0; pp < 13; ++pp) {
        const int s = pp * 16 + w * 2 + rh;
        float a = 0.f;
        if (s < NS) {
          const float* kr = p.keys + ((size_t)b * NS + s) * NK + kl * 4;
#pragma unroll
          for (int i = 0; i < 2; ++i) {
            const float4 k4 = *(const float4*)(kr + i * 128);
            const float4 q4 = *(const float4*)(attq + i * 128 + kl * 4);
            a += k4.x * q4.x + k4.y * q4.y + k4.z * q4.z + k4.w * q4.w;
          }
        }
#pragma unroll
        for (int mk = 1; mk < 32; mk <<= 1) a += __shfl_xor(a, mk);
        if (kl == 0 && s < NS) smx[s] = a;
      }
      __syncthreads();
      float e = -INFINITY;
      if (t < 256) { e = (t < NS) ? smx[t] : -INFINITY; red[t] = e; }
      __syncthreads();
      for (int off = 128; off; off >>= 1) {
        if (t < off) red[t] = fmaxf(red[t], red[t + off]);
        __syncthreads();
      }
      const float mx = red[0];
      __syncthreads();
      float a = 0.f;
      if (t < 256) { a = (t < NS) ? expf(e - mx) : 0.f; red[t] = a; }
      __syncthreads();
      for (int off = 128; off; off >>= 1) {
        if (t < off) red[t] += red[t + off];
        __syncthreads();
      }
      const float inv = 1.0f / red[0];
      if (t < 256) smx[t] = a * inv;
      __syncthreads();
      if (t < 256) {
        const float* vb = p.values + (size_t)b * NS * NK + t;
        float c0_ = 0.f, c1_ = 0.f, c2_ = 0.f, c3_ = 0.f;
        for (int s = 0; s < NS; s += 4) {
          c0_ += smx[s + 0] * vb[(size_t)(s + 0) * NK];
          c1_ += smx[s + 1] * vb[(size_t)(s + 1) * NK];
          c2_ += smx[s + 2] * vb[(size_t)(s + 2) * NK];
          c3_ += smx[s + 3] * vb[(size_t)(s + 3) * NK];
        }
        astf(&p.ctx[t * 32 + b], (c0_ + c1_) + (c2_ + c3_));
      }
    }
    gbar(p.bar, bid, ep++, false);

    // ===== P5: pred GEMV from LDS-pinned Wp; 6 staged chunks of [128k][32b] =====
    if (bid < 250) {
      const int bh = lane & 15, kq = (lane >> 4) & 3;
      const int rloc = w * 5;
      const int rbase = bid * 40 + rloc;
      float acc[5][2];
#pragma unroll
      for (int r = 0; r < 5; ++r) { acc[r][0] = 0.f; acc[r][1] = 0.f; }
      for (int c = 0; c < 6; ++c) {
        {
          const float* srcm = (c < 4) ? (h1n + c * 4096) : (p.ctx + (c - 4) * 4096);
          const int b2 = t & 31, kg = t >> 5;
#pragma unroll
          for (int kk = 0; kk < 8; ++kk) {
            const int k = kg * 8 + kk;
            stage[4 * eslot(b2, k >> 2) + (k & 3)] = aldf(srcm + k * 32 + b2);
          }
        }
        __syncthreads();
#pragma unroll
        for (int j = 0; j < 8; ++j) {
          const int f4 = j * 4 + kq;
          const int s0 = 4 * eslot(bh, f4), s1 = 4 * eslot(bh + 16, f4);
          const float x00 = stage[s0 + 0], x10 = stage[s0 + 1];
          const float x20 = stage[s0 + 2], x30 = stage[s0 + 3];
          const float x01 = stage[s1 + 0], x11 = stage[s1 + 1];
          const float x21 = stage[s1 + 2], x31 = stage[s1 + 3];
          const int wc = c * 128 + 4 * f4;
#pragma unroll
          for (int r = 0; r < 5; ++r) {
            const float4 w4 = *(const float4*)(Wp_lds + (rloc + r) * 768 + wc);
            acc[r][0] += w4.x * x00 + w4.y * x10 + w4.z * x20 + w4.w * x30;
            acc[r][1] += w4.x * x01 + w4.y * x11 + w4.z * x21 + w4.w * x31;
          }
        }
        __syncthreads();
      }
#pragma unroll
      for (int r = 0; r < 5; ++r) {
#pragma unroll
        for (int u = 0; u < 2; ++u) {
          acc[r][u] += __shfl_xor(acc[r][u], 16);
          acc[r][u] += __shfl_xor(acc[r][u], 32);
        }
      }
      if (kq == 0) {
#pragma unroll
        for (int u = 0; u < 2; ++u) {
          const int b = bh + u * 16;
          const size_t ro = ((size_t)b * NT + step) * NV + rbase;
          u64 m = 0ull;
#pragma unroll
          for (int r = 0; r < 5; ++r) {
            const float v = acc[r][u] + p.bp[rbase + r];
            __builtin_nontemporal_store(v, &p.out[ro + r]);
            const u64 pk = packmax(v, rbase + r);
            if (pk > m) m = pk;
          }
          cand[w][b] = m;
        }
      }
      __syncthreads();
      if (t < 32) {
        u64 mm = cand[0][t];
#pragma unroll
        for (int i = 1; i < 8; ++i) { const u64 o = cand[i][t]; if (o > mm) mm = o; }
        (void)__hip_atomic_fetch_max(&p.amax[(bid & 7) * 32 + t], mm, __ATOMIC_RELAXED, SCOPE);
      }
    }
    gbar(p.bar, bid, ep++, false);
  }
}

// ---------------- host ----------------
extern "C" void kernel_launch(void* const* d_in, const int* in_sizes, int n_in,
                              void* d_out, int out_size, void* d_ws, size_t ws_size,
                              hipStream_t stream) {
  (void)in_sizes; (void)n_in; (void)out_size; (void)ws_size;
  Params prm;
  prm.x    = (const float*)d_in[0];
  prm.emb  = (const float*)d_in[1];
  prm.Wk   = (const float*)d_in[2];
  prm.bk   = (const float*)d_in[3];
  prm.Wv   = (const float*)d_in[4];
  prm.bv   = (const float*)d_in[5];
  prm.Wq   = (const float*)d_in[6];
  prm.bq   = (const float*)d_in[7];
  prm.Wp   = (const float*)d_in[8];
  prm.bp   = (const float*)d_in[9];
  prm.Wih0 = (const float*)d_in[10];
  prm.Whh0 = (const float*)d_in[11];
  prm.bih0 = (const float*)d_in[12];
  prm.bhh0 = (const float*)d_in[13];
  prm.Wih1 = (const float*)d_in[14];
  prm.Whh1 = (const float*)d_in[15];
  prm.bih1 = (const float*)d_in[16];
  prm.bhh1 = (const float*)d_in[17];
  prm.out  = (float*)d_out;

  float* ws = (float*)d_ws;
  prm.keys   = ws;                          // 1,605,632
  prm.values = prm.keys + 1605632;          // 1,605,632
  prm.h0t    = prm.values + 1605632;        // [2][512][32] = 32,768 (zero region start)
  prm.h1t    = prm.h0t + 32768;             // 32,768
  prm.c0     = prm.h1t + 32768;             // 16,384
  prm.c1     = prm.c0 + 16384;              // 16,384
  prm.ctx    = prm.c1 + 16384;              // [256][32] = 8,192
  prm.amax   = (u64*)(prm.ctx + 8192);      // 256 u64 = 512 f
  prm.qg     = prm.ctx + 8192 + 512;        // [256][32] = 8,192
  prm.bar    = (unsigned*)(prm.qg + 8192);  // 1,024 u32 barrier state

  const int LDS = (30720 + 4096) * 4;       // 139,264 B dynamic
  (void)hipFuncSetAttribute((const void*)k_all, hipFuncAttributeMaxDynamicSharedMemorySize, LDS);

  k_zbar<<<4, 256, 0, stream>>>(prm.bar);   // reset barrier state (graph-safe)
  void* args[] = { &prm };
  (void)hipLaunchCooperativeKernel((const void*)k_all, dim3(NBLK), dim3(NTHR), args,
                                   (unsigned)LDS, stream);
}